// Round 4
// baseline (399.888 us; speedup 1.0000x reference)
//
#include <hip/hip_runtime.h>

#define N_E   1024
#define E_DIM 512
#define HW_   4096
#define NVEC  65536                 // 16 * 64 * 64
#define ZQ_ELEMS 33554432           // 16*512*64*64
#define BETA 0.25f

typedef _Float16 half8 __attribute__((ext_vector_type(8), aligned(16)));
typedef float f32x4 __attribute__((ext_vector_type(4)));
typedef unsigned int u32x4 __attribute__((ext_vector_type(4), aligned(16)));

union H16 { _Float16 f; unsigned short u; };
__device__ __forceinline__ unsigned short f2h(float v) { H16 h; h.f = (_Float16)v; return h.u; }

// ---------------- prep: codebook -> fp16 hi/lo (x32), ynorm (x1024) ----------------
__global__ __launch_bounds__(64) void vq_prep(const float* __restrict__ cb,
    unsigned short* __restrict__ Bh, unsigned short* __restrict__ Bl,
    float* __restrict__ ynorm) {
    int j = blockIdx.x, l = threadIdx.x;
    float s = 0.f;
    for (int i = 0; i < 8; ++i) {
        int c = l + (i << 6);
        float v = cb[(j << 9) + c];
        s += v * v;
        float vs = 32.f * v;
        _Float16 hi = (_Float16)vs;
        H16 hh; hh.f = hi;
        Bh[(j << 9) + c] = hh.u;
        Bl[(j << 9) + c] = f2h(vs - (float)hi);
    }
#pragma unroll
    for (int off = 32; off > 0; off >>= 1) s += __shfl_xor(s, off);
    if (l == 0) ynorm[j] = s * 1024.f;        // scaled by 32^2 to match scaled dot
}

// ---------------- pack: z -> A[m][k] fp16 hi/lo (x32) + ||z||^2 block partials ----------------
__global__ __launch_bounds__(256) void vq_pack(const float* __restrict__ z,
    unsigned short* __restrict__ Ah, unsigned short* __restrict__ Al,
    float* __restrict__ zpart, int base_b, int bid0) {
    __shared__ float T[64][65];
    __shared__ float ps[4];
    int bid = blockIdx.x;
    int hw0 = (bid & 63) << 6;
    int c0 = ((bid >> 6) & 7) << 6;
    int bb = (bid >> 9) + base_b;
    int t = threadIdx.x;
    int hl = t & 63, cl = t >> 6;
    const float* zp = z + ((long)((bb << 9) + c0 + cl)) * 4096 + hw0 + hl;
#pragma unroll
    for (int i = 0; i < 16; ++i)
        T[cl + 4 * i][hl] = zp[(long)(4 * i) * 4096];
    __syncthreads();
    int hr = t >> 2, cg = (t & 3) << 4;
    long m = ((long)(bb - base_b) << 12) + hw0 + hr;   // phase-local row
    unsigned short h8[16], l8[16];
    float s = 0.f;
#pragma unroll
    for (int e = 0; e < 16; ++e) {
        float v0 = T[cg + e][hr];
        s += v0 * v0;
        float v = 32.f * v0;
        _Float16 hi = (_Float16)v;
        H16 hh; hh.f = hi;
        h8[e] = hh.u;
        l8[e] = f2h(v - (float)hi);
    }
    long o = m * 512 + c0 + cg;
    *(u32x4*)&Ah[o]     = *(u32x4*)&h8[0];
    *(u32x4*)&Ah[o + 8] = *(u32x4*)&h8[8];
    *(u32x4*)&Al[o]     = *(u32x4*)&l8[0];
    *(u32x4*)&Al[o + 8] = *(u32x4*)&l8[8];
#pragma unroll
    for (int off = 32; off > 0; off >>= 1) s += __shfl_xor(s, off);
    if ((t & 63) == 0) ps[t >> 6] = s;
    __syncthreads();
    if (t == 0) zpart[bid0 + bid] = ps[0] + ps[1] + ps[2] + ps[3];
}

// ---------------- dist: MFMA fp16-split GEMM + fused argmin (80 KB LDS, 2 blocks/CU) ----------------
// 512 threads (8 waves: 2m x 4j), block tile 128m x 512j, 2 j-passes x 16 K-chunks of 32.
// Single-buffered LDS; reg-staged issue-early/write-late; argmin kept in registers.
__global__ __launch_bounds__(512, 2) void vq_dist(
    const unsigned short* __restrict__ Ah, const unsigned short* __restrict__ Al,
    const unsigned short* __restrict__ Bh, const unsigned short* __restrict__ Bl,
    const float* __restrict__ ynorm, int* __restrict__ ws_idx,
    float* __restrict__ out_idx, float* __restrict__ dpart, int mbase) {

    __shared__ _Float16 sA[128][64];        // 16 KB, slot-swizzled [m][hi 0..31 | lo 32..63]
    __shared__ _Float16 sB[512][64];        // 64 KB, single-buffered

    const int t = threadIdx.x;
    const int l = t & 63, wid = t >> 6;
    const int lid = l & 15, kg = l >> 4;
    const int wm64 = (wid >> 2) << 6;       // 0 or 64
    const int wj128 = (wid & 3) << 7;       // 0..384
    const int m0 = blockIdx.x << 7;         // phase-local m base

    // A staging: row = t&127, quarter = t>>7 (0,1 = hi halves; 2,3 = lo halves)
    const int arow = t & 127;
    const int apart = t >> 7;
    const unsigned short* Agp = (apart < 2 ? Ah : Al)
        + (((long)(m0 + arow)) << 9) + ((apart & 1) << 4);
    const int aslot = apart << 1;
    const int ax = arow & 7;
    // B staging: thread t owns row t (4 hi + 4 lo u32x4)
    const int bx = t & 7;
    const unsigned short* Bh_row = Bh + ((long)t << 9);
    const unsigned short* Bl_row = Bl + ((long)t << 9);

    u32x4 ra0, ra1, rb0, rb1, rb2, rb3, rb4, rb5, rb6, rb7;

    auto LOAD = [&](int c) {
        const int kc = (c & 15) << 5;
        const long po = ((long)(c >> 4)) << 18;          // pass*512 rows * 512 halves
        const unsigned short* ph = Bh_row + po + kc;
        const unsigned short* pl = Bl_row + po + kc;
        rb0 = *(const u32x4*)(ph);      rb1 = *(const u32x4*)(ph + 8);
        rb2 = *(const u32x4*)(ph + 16); rb3 = *(const u32x4*)(ph + 24);
        rb4 = *(const u32x4*)(pl);      rb5 = *(const u32x4*)(pl + 8);
        rb6 = *(const u32x4*)(pl + 16); rb7 = *(const u32x4*)(pl + 24);
        ra0 = *(const u32x4*)(Agp + kc);
        ra1 = *(const u32x4*)(Agp + kc + 8);
    };
    auto STORE = [&]() {
        *(u32x4*)&sA[arow][(aslot ^ ax) << 3]       = ra0;
        *(u32x4*)&sA[arow][((aslot + 1) ^ ax) << 3] = ra1;
        *(u32x4*)&sB[t][(0 ^ bx) << 3] = rb0;  *(u32x4*)&sB[t][(1 ^ bx) << 3] = rb1;
        *(u32x4*)&sB[t][(2 ^ bx) << 3] = rb2;  *(u32x4*)&sB[t][(3 ^ bx) << 3] = rb3;
        *(u32x4*)&sB[t][(4 ^ bx) << 3] = rb4;  *(u32x4*)&sB[t][(5 ^ bx) << 3] = rb5;
        *(u32x4*)&sB[t][(6 ^ bx) << 3] = rb6;  *(u32x4*)&sB[t][(7 ^ bx) << 3] = rb7;
    };

    f32x4 acc[4][8];
    auto ZERO = [&]() {
#pragma unroll
        for (int mt = 0; mt < 4; ++mt)
#pragma unroll
            for (int jt = 0; jt < 8; ++jt) acc[mt][jt] = {0.f, 0.f, 0.f, 0.f};
    };
    auto COMPUTE = [&]() {
        half8 ah[4], alo[4];
#pragma unroll
        for (int mt = 0; mt < 4; ++mt) {
            int row = wm64 + (mt << 4) + lid;
            ah[mt]  = *(const half8*)&sA[row][(kg ^ (row & 7)) << 3];
            alo[mt] = *(const half8*)&sA[row][((4 + kg) ^ (row & 7)) << 3];
        }
#pragma unroll
        for (int jt = 0; jt < 8; ++jt) {
            int row = wj128 + (jt << 4) + lid;
            half8 bh = *(const half8*)&sB[row][(kg ^ (row & 7)) << 3];
            half8 bl = *(const half8*)&sB[row][((4 + kg) ^ (row & 7)) << 3];
#pragma unroll
            for (int mt = 0; mt < 4; ++mt) {
                acc[mt][jt] = __builtin_amdgcn_mfma_f32_16x16x32_f16(ah[mt],  bh, acc[mt][jt], 0, 0, 0);
                acc[mt][jt] = __builtin_amdgcn_mfma_f32_16x16x32_f16(alo[mt], bh, acc[mt][jt], 0, 0, 0);
                acc[mt][jt] = __builtin_amdgcn_mfma_f32_16x16x32_f16(ah[mt],  bl, acc[mt][jt], 0, 0, 0);
            }
        }
    };

    float bd[4][4]; int bj[4][4];           // per-thread running best (d, j)
#pragma unroll
    for (int mt = 0; mt < 4; ++mt)
#pragma unroll
        for (int r = 0; r < 4; ++r) { bd[mt][r] = 3.4e38f; bj[mt][r] = 0x7fffffff; }

    LOAD(0);
    ZERO();
    for (int c = 0; c < 32; ++c) {
        __syncthreads();                    // previous chunk's readers done
        STORE();                            // write chunk c (vmcnt auto-inserted)
        __syncthreads();                    // chunk c visible
        if (c < 31) LOAD(c + 1);            // issue next-chunk globals (hide under MFMA)
        COMPUTE();
        if ((c & 15) == 15) {               // end of a j-pass: fold acc into running best
            int pass = c >> 4;
            float yn[8];
#pragma unroll
            for (int jt = 0; jt < 8; ++jt)
                yn[jt] = ynorm[(pass << 9) + wj128 + (jt << 4) + lid];
#pragma unroll
            for (int mt = 0; mt < 4; ++mt)
#pragma unroll
                for (int r = 0; r < 4; ++r) {
#pragma unroll
                    for (int jt = 0; jt < 8; ++jt) {
                        int jg = (pass << 9) + wj128 + (jt << 4) + lid;
                        float d = yn[jt] - 2.f * acc[mt][jt][r];
                        if (d < bd[mt][r] || (d == bd[mt][r] && jg < bj[mt][r])) {
                            bd[mt][r] = d; bj[mt][r] = jg;
                        }
                    }
                }
            ZERO();
        }
    }

    // cross-lane reduce over the 16 j-columns (lid), lexicographic (d, j)
#pragma unroll
    for (int off = 1; off < 16; off <<= 1)
#pragma unroll
        for (int mt = 0; mt < 4; ++mt)
#pragma unroll
            for (int r = 0; r < 4; ++r) {
                float od = __shfl_xor(bd[mt][r], off);
                int   oj = __shfl_xor(bj[mt][r], off);
                if (od < bd[mt][r] || (od == bd[mt][r] && oj < bj[mt][r])) {
                    bd[mt][r] = od; bj[mt][r] = oj;
                }
            }

    __syncthreads();                        // all compute done: sA is dead, alias it
    float* mrgd = (float*)&sA[0][0];        // [8][4][4][4] = 2 KB
    int*   mrgj = (int*)(mrgd + 512);       // 2 KB
    float* psumf = mrgd + 1024;             // 2 floats
    if (lid == 0) {
#pragma unroll
        for (int mt = 0; mt < 4; ++mt)
#pragma unroll
            for (int r = 0; r < 4; ++r) {
                int idx = (wid << 6) + (kg << 4) + (mt << 2) + r;
                mrgd[idx] = bd[mt][r]; mrgj[idx] = bj[mt][r];
            }
    }
    __syncthreads();

    float myd = 0.f;
    if (t < 128) {                          // one thread per m row
        int wmv = t >> 6, local = t & 63;
        int mt = local >> 4, kg2 = (local >> 2) & 3, r = local & 3;
        float bD = 3.4e38f; int bJ = 0x7fffffff;
#pragma unroll
        for (int wjv = 0; wjv < 4; ++wjv) {
            int idx = (((wmv << 2) + wjv) << 6) + (kg2 << 4) + (mt << 2) + r;
            float od = mrgd[idx]; int oj = mrgj[idx];
            if (od < bD || (od == bD && oj < bJ)) { bD = od; bJ = oj; }
        }
        int m = mbase + m0 + (wmv << 6) + (mt << 4) + (kg2 << 2) + r;
        ws_idx[m] = bJ;
        out_idx[m] = (float)bJ;
        myd = bD;                           // scaled distance missing ||z||^2 (added in final)
    }
    if (wid < 2) {                          // block partial of sum(bestd)
#pragma unroll
        for (int off = 32; off > 0; off >>= 1) myd += __shfl_xor(myd, off);
        if (l == 0) psumf[wid] = myd;
    }
    __syncthreads();
    if (t == 0) dpart[(mbase >> 7) + blockIdx.x] = psumf[0] + psumf[1];
}

// ---------------- gather: pure scatter of codebook rows into (B,C,H,W) ----------------
__global__ __launch_bounds__(256) void vq_gather(const float* __restrict__ cb,
    const int* __restrict__ ws_idx, float* __restrict__ out) {
    int base = blockIdx.x * 256 + threadIdx.x;   // 2^21 threads
    int hw  = base & 4095;
    int c4g = (base >> 12) & 31;
    int b   = base >> 17;
    int j   = ws_idx[(b << 12) | hw];
#pragma unroll
    for (int it = 0; it < 4; ++it) {
        int c4 = (c4g << 2) + it;
        float4 v = ((const float4*)cb)[(j << 7) + c4];
        long zo = ((long)((b << 9) + (c4 << 2))) * 4096 + hw;
        out[zo] = v.x; out[zo + 4096] = v.y; out[zo + 8192] = v.z; out[zo + 12288] = v.w;
    }
}

// ---------------- final: loss = 1.25 * (sum(bestd)/1024 + sum||z||^2) / numel ----------------
__global__ __launch_bounds__(1024) void vq_final(const float* __restrict__ dpart,
    const float* __restrict__ zpart, float* __restrict__ out) {
    int t = threadIdx.x;
    double s = 0.0;
    if (t < 512) s += (double)dpart[t] * (1.0 / 1024.0);
#pragma unroll
    for (int i = 0; i < 8; ++i) s += (double)zpart[t + (i << 10)];
#pragma unroll
    for (int off = 32; off > 0; off >>= 1) s += __shfl_xor(s, off);
    __shared__ double pd[16];
    if ((t & 63) == 0) pd[t >> 6] = s;
    __syncthreads();
    if (t == 0) {
        double tot = 0.0;
#pragma unroll
        for (int i = 0; i < 16; ++i) tot += pd[i];
        out[ZQ_ELEMS] = (float)(1.25 * tot / 33554432.0);
    }
}

extern "C" void kernel_launch(void* const* d_in, const int* in_sizes, int n_in,
                              void* d_out, int out_size, void* d_ws, size_t ws_size,
                              hipStream_t stream) {
    const float* z  = (const float*)d_in[0];   // (16,512,64,64) fp32
    const float* cb = (const float*)d_in[1];   // (1024,512) fp32
    float* out = (float*)d_out;                // [z_q | loss | indices(float)]
    char* ws = (char*)d_ws;

    float* ynorm    = (float*)(ws + 1024);                // 4 KB
    int*   ws_idx   = (int*)(ws + 8192);                  // 256 KB
    float* dpart    = (float*)(ws + 272 * 1024);          // 2 KB (512 floats)
    float* zpart    = (float*)(ws + 288 * 1024);          // 32 KB (8192 floats)
    unsigned short* Bh = (unsigned short*)(ws + (1L << 20));
    unsigned short* Bl = (unsigned short*)(ws + (2L << 20));
    const size_t base = 3L << 20;
    unsigned short* Ah = (unsigned short*)(ws + base);

    // pick M-phasing from available workspace (deterministic in ws_size)
    int nphase = 1;
    while (nphase < 16) {
        size_t Asz = (size_t)(65536 / nphase) * 512 * 2;
        if (base + 2 * Asz <= ws_size) break;
        nphase <<= 1;
    }
    size_t Asz = (size_t)(65536 / nphase) * 512 * 2;
    unsigned short* Al = (unsigned short*)(ws + base + Asz);

    vq_prep<<<N_E, 64, 0, stream>>>(cb, Bh, Bl, ynorm);
    int PM = 65536 / nphase;
    for (int p = 0; p < nphase; ++p) {
        vq_pack<<<8192 / nphase, 256, 0, stream>>>(z, Ah, Al, zpart,
                                                   p * (16 / nphase),
                                                   p * (8192 / nphase));
        vq_dist<<<PM / 128, 512, 0, stream>>>(Ah, Al, Bh, Bl, ynorm, ws_idx,
                                              out + ZQ_ELEMS + 1, dpart, p * PM);
    }
    vq_gather<<<NVEC / 256 * 32, 256, 0, stream>>>(cb, ws_idx, out);
    vq_final<<<1, 1024, 0, stream>>>(dpart, zpart, out);
}

// Round 5
// 292.251 us; speedup vs baseline: 1.3683x; 1.3683x over previous
//
#include <hip/hip_runtime.h>

#define N_E   1024
#define E_DIM 512
#define HW_   4096
#define NVEC  65536                 // 16 * 64 * 64
#define ZQ_ELEMS 33554432           // 16*512*64*64
#define BETA 0.25f

typedef _Float16 half8 __attribute__((ext_vector_type(8), aligned(16)));
typedef float f32x4 __attribute__((ext_vector_type(4)));
typedef unsigned int u32x4 __attribute__((ext_vector_type(4), aligned(16)));

union H16 { _Float16 f; unsigned short u; };
__device__ __forceinline__ unsigned short f2h(float v) { H16 h; h.f = (_Float16)v; return h.u; }

// direct-to-LDS DMA: per-lane global src, wave-uniform LDS base + lane*16
#define GLDS(gp, lp) __builtin_amdgcn_global_load_lds( \
    (const __attribute__((address_space(1))) void*)(gp), \
    (__attribute__((address_space(3))) void*)(lp), 16, 0, 0)

// ---------------- prep: codebook -> fp16 hi/lo (x32), ynorm (x1024) ----------------
__global__ __launch_bounds__(64) void vq_prep(const float* __restrict__ cb,
    unsigned short* __restrict__ Bh, unsigned short* __restrict__ Bl,
    float* __restrict__ ynorm) {
    int j = blockIdx.x, l = threadIdx.x;
    float s = 0.f;
    for (int i = 0; i < 8; ++i) {
        int c = l + (i << 6);
        float v = cb[(j << 9) + c];
        s += v * v;
        float vs = 32.f * v;
        _Float16 hi = (_Float16)vs;
        H16 hh; hh.f = hi;
        Bh[(j << 9) + c] = hh.u;
        Bl[(j << 9) + c] = f2h(vs - (float)hi);
    }
#pragma unroll
    for (int off = 32; off > 0; off >>= 1) s += __shfl_xor(s, off);
    if (l == 0) ynorm[j] = s * 1024.f;        // scaled by 32^2 to match scaled dot
}

// ---------------- pack: z -> A[m][k] fp16 hi/lo (x32) + ||z||^2 block partials ----------------
__global__ __launch_bounds__(256) void vq_pack(const float* __restrict__ z,
    unsigned short* __restrict__ Ah, unsigned short* __restrict__ Al,
    float* __restrict__ zpart, int base_b, int bid0) {
    __shared__ float T[64][65];
    __shared__ float ps[4];
    int bid = blockIdx.x;
    int hw0 = (bid & 63) << 6;
    int c0 = ((bid >> 6) & 7) << 6;
    int bb = (bid >> 9) + base_b;
    int t = threadIdx.x;
    int hl = t & 63, cl = t >> 6;
    const float* zp = z + ((long)((bb << 9) + c0 + cl)) * 4096 + hw0 + hl;
#pragma unroll
    for (int i = 0; i < 16; ++i)
        T[cl + 4 * i][hl] = zp[(long)(4 * i) * 4096];
    __syncthreads();
    int hr = t >> 2, cg = (t & 3) << 4;
    long m = ((long)(bb - base_b) << 12) + hw0 + hr;   // phase-local row
    unsigned short h8[16], l8[16];
    float s = 0.f;
#pragma unroll
    for (int e = 0; e < 16; ++e) {
        float v0 = T[cg + e][hr];
        s += v0 * v0;
        float v = 32.f * v0;
        _Float16 hi = (_Float16)v;
        H16 hh; hh.f = hi;
        h8[e] = hh.u;
        l8[e] = f2h(v - (float)hi);
    }
    long o = m * 512 + c0 + cg;
    *(u32x4*)&Ah[o]     = *(u32x4*)&h8[0];
    *(u32x4*)&Ah[o + 8] = *(u32x4*)&h8[8];
    *(u32x4*)&Al[o]     = *(u32x4*)&l8[0];
    *(u32x4*)&Al[o + 8] = *(u32x4*)&l8[8];
#pragma unroll
    for (int off = 32; off > 0; off >>= 1) s += __shfl_xor(s, off);
    if ((t & 63) == 0) ps[t >> 6] = s;
    __syncthreads();
    if (t == 0) zpart[bid0 + bid] = ps[0] + ps[1] + ps[2] + ps[3];
}

// ---------------- dist: MFMA fp16-split GEMM + fused argmin ----------------
// 512 threads (8 waves: 4m x 2j), block tile 256m x 256j, 4 j-passes x 16 K-chunks of 32.
// Double-buffered A+B (128 KB LDS), global_load_lds staging (linear LDS dest,
// inverse-XOR-swizzled per-lane global source), stage issued BEFORE compute so the
// __syncthreads vmcnt drain is fully covered by the MFMA chunk (~3700 cyc >> HBM lat).
__global__ __launch_bounds__(512, 2) void vq_dist(
    const unsigned short* __restrict__ Ah, const unsigned short* __restrict__ Al,
    const unsigned short* __restrict__ Bh, const unsigned short* __restrict__ Bl,
    const float* __restrict__ ynorm, int* __restrict__ ws_idx,
    float* __restrict__ out_idx, float* __restrict__ dpart, int mbase) {

    __shared__ _Float16 sA[2][256][64];     // 64 KB  [buf][m][slots: hi 0..3 | lo 4..7, XOR row&7]
    __shared__ _Float16 sB[2][256][64];     // 64 KB

    const int t = threadIdx.x;
    const int l = t & 63, wid = t >> 6;
    const int lid = l & 15, kg = l >> 4;
    const int wm = (wid >> 1) << 6;         // 4 m-wave-groups of 64 rows
    const int wj = (wid & 1) << 7;          // 2 j-wave-groups of 128 cols
    const int m0 = blockIdx.x << 8;         // 256 m rows per block

    // staging geometry: one GLDS instr writes 1 KB = 8 LDS rows x 8 slots(16B).
    // lane l -> row r8 = l>>3 within group, slot sl = l&7. LDS[r][q] must hold
    // source slot q^(r&7)  (the read-side swizzle), so lane loads source slot
    // st = sl ^ r8; st<4 -> hi k-group (st&3), st>=4 -> lo k-group.
    const int r8 = l >> 3, sl = l & 7, st = sl ^ r8;
    const unsigned short* Asrc = (st & 4) ? Al : Ah;
    const unsigned short* Bsrc = (st & 4) ? Bl : Bh;
    const unsigned short* gpA0 = Asrc + ((long)(m0 + (wid << 3) + r8) << 9) + ((st & 3) << 3);
    const unsigned short* gpB0 = Bsrc + ((long)((wid << 3) + r8) << 9) + ((st & 3) << 3);

    auto STAGE = [&](int buf, int k, int p) {
        const long ao = (long)k << 5;                 // k-chunk offset (halves)
        const long bo = ao + ((long)p << 17);         // + pass*256rows*512
#pragma unroll
        for (int g = 0; g < 4; ++g) {                 // wave handles row-groups wid, wid+8, ...
            GLDS(gpA0 + ao + ((long)g << 15), &sA[buf][(wid + (g << 3)) << 3][0]);
            GLDS(gpB0 + bo + ((long)g << 15), &sB[buf][(wid + (g << 3)) << 3][0]);
        }
    };

    f32x4 acc[4][8];
    auto ZERO = [&]() {
#pragma unroll
        for (int mt = 0; mt < 4; ++mt)
#pragma unroll
            for (int jt = 0; jt < 8; ++jt) acc[mt][jt] = {0.f, 0.f, 0.f, 0.f};
    };

    auto COMPUTE = [&](int buf) {
        half8 ah[4], alo[4];
#pragma unroll
        for (int mt = 0; mt < 4; ++mt) {
            int row = wm + (mt << 4) + lid;
            ah[mt]  = *(const half8*)&sA[buf][row][(kg ^ (row & 7)) << 3];
            alo[mt] = *(const half8*)&sA[buf][row][((4 + kg) ^ (row & 7)) << 3];
        }
#pragma unroll
        for (int jt = 0; jt < 8; ++jt) {
            int row = wj + (jt << 4) + lid;
            half8 bh = *(const half8*)&sB[buf][row][(kg ^ (row & 7)) << 3];
            half8 bl = *(const half8*)&sB[buf][row][((4 + kg) ^ (row & 7)) << 3];
#pragma unroll
            for (int mt = 0; mt < 4; ++mt) {
                acc[mt][jt] = __builtin_amdgcn_mfma_f32_16x16x32_f16(ah[mt],  bh, acc[mt][jt], 0, 0, 0);
                acc[mt][jt] = __builtin_amdgcn_mfma_f32_16x16x32_f16(alo[mt], bh, acc[mt][jt], 0, 0, 0);
                acc[mt][jt] = __builtin_amdgcn_mfma_f32_16x16x32_f16(ah[mt],  bl, acc[mt][jt], 0, 0, 0);
            }
        }
    };

    float bd[4][4]; int bj[4][4];           // per-thread running best (d, j)
#pragma unroll
    for (int mt = 0; mt < 4; ++mt)
#pragma unroll
        for (int r = 0; r < 4; ++r) { bd[mt][r] = 3.4e38f; bj[mt][r] = 0x7fffffff; }

    auto FOLD = [&](int p) {
#pragma unroll
        for (int jt = 0; jt < 8; ++jt) {
            int jg = (p << 8) + wj + (jt << 4) + lid;
            float yn = ynorm[jg];
#pragma unroll
            for (int mt = 0; mt < 4; ++mt)
#pragma unroll
                for (int r = 0; r < 4; ++r) {
                    float d = yn - 2.f * acc[mt][jt][r];
                    if (d < bd[mt][r] || (d == bd[mt][r] && jg < bj[mt][r])) {
                        bd[mt][r] = d; bj[mt][r] = jg;
                    }
                }
        }
    };

    // prologue: stage slot 0 (pass 0, k 0); barrier drains the DMA
    STAGE(0, 0, 0);
    ZERO();
    __syncthreads();

    int cur = 0;
    for (int s = 0; s < 64; ++s) {          // 4 passes x 16 k-chunks
        if (s < 63) { int n = s + 1; STAGE(cur ^ 1, n & 15, n >> 4); }
        COMPUTE(cur);
        if ((s & 15) == 15) { FOLD(s >> 4); ZERO(); }
        __syncthreads();                    // vmcnt drain covered by COMPUTE
        cur ^= 1;
    }

    // cross-lane reduce over the 16 j-columns (lid), lexicographic (d, j)
#pragma unroll
    for (int off = 1; off < 16; off <<= 1)
#pragma unroll
        for (int mt = 0; mt < 4; ++mt)
#pragma unroll
            for (int r = 0; r < 4; ++r) {
                float od = __shfl_xor(bd[mt][r], off);
                int   oj = __shfl_xor(bj[mt][r], off);
                if (od < bd[mt][r] || (od == bd[mt][r] && oj < bj[mt][r])) {
                    bd[mt][r] = od; bj[mt][r] = oj;
                }
            }

    // merge the 2 j-wave-groups via LDS (sA is dead, alias it)
    float* mrgd = (float*)&sA[0][0][0];     // 512 floats
    int*   mrgj = (int*)(mrgd + 512);       // 512 ints
    float* psumf = (float*)(mrgj + 512);    // 8 floats
    if (lid == 0) {
#pragma unroll
        for (int mt = 0; mt < 4; ++mt)
#pragma unroll
            for (int r = 0; r < 4; ++r) {
                int idx = (wid << 6) + (mt << 4) + (kg << 2) + r;
                mrgd[idx] = bd[mt][r]; mrgj[idx] = bj[mt][r];
            }
    }
    __syncthreads();

    float myd = 0.f;
    if (t < 256) {                          // one thread per m row: t = wmv*64+mt*16+kg*4+r
        int wmv = t >> 6, mt = (t >> 4) & 3, kg2 = (t >> 2) & 3, r = t & 3;
        float bD = 3.4e38f; int bJ = 0x7fffffff;
#pragma unroll
        for (int wjv = 0; wjv < 2; ++wjv) {
            int idx = (((wmv << 1) + wjv) << 6) + (mt << 4) + (kg2 << 2) + r;
            float od = mrgd[idx]; int oj = mrgj[idx];
            if (od < bD || (od == bD && oj < bJ)) { bD = od; bJ = oj; }
        }
        int m = mbase + m0 + t;
        ws_idx[m] = bJ;
        out_idx[m] = (float)bJ;
        myd = bD;                           // scaled distance missing ||z||^2 (added in final)
    }
#pragma unroll
    for (int off = 32; off > 0; off >>= 1) myd += __shfl_xor(myd, off);
    if (l == 0) psumf[wid] = myd;
    __syncthreads();
    if (t == 0) {
        float tot = 0.f;
#pragma unroll
        for (int i = 0; i < 8; ++i) tot += psumf[i];
        dpart[(mbase >> 8) + blockIdx.x] = tot;
    }
}

// ---------------- gather: pure scatter of codebook rows into (B,C,H,W) ----------------
__global__ __launch_bounds__(256) void vq_gather(const float* __restrict__ cb,
    const int* __restrict__ ws_idx, float* __restrict__ out) {
    int base = blockIdx.x * 256 + threadIdx.x;   // 2^21 threads
    int hw  = base & 4095;
    int c4g = (base >> 12) & 31;
    int b   = base >> 17;
    int j   = ws_idx[(b << 12) | hw];
#pragma unroll
    for (int it = 0; it < 4; ++it) {
        int c4 = (c4g << 2) + it;
        float4 v = ((const float4*)cb)[(j << 7) + c4];
        long zo = ((long)((b << 9) + (c4 << 2))) * 4096 + hw;
        out[zo] = v.x; out[zo + 4096] = v.y; out[zo + 8192] = v.z; out[zo + 12288] = v.w;
    }
}

// ---------------- final: loss = 1.25 * (sum(bestd)/1024 + sum||z||^2) / numel ----------------
__global__ __launch_bounds__(1024) void vq_final(const float* __restrict__ dpart,
    const float* __restrict__ zpart, float* __restrict__ out) {
    int t = threadIdx.x;
    double s = 0.0;
    if (t < 256) s += (double)dpart[t] * (1.0 / 1024.0);
#pragma unroll
    for (int i = 0; i < 8; ++i) s += (double)zpart[t + (i << 10)];
#pragma unroll
    for (int off = 32; off > 0; off >>= 1) s += __shfl_xor(s, off);
    __shared__ double pd[16];
    if ((t & 63) == 0) pd[t >> 6] = s;
    __syncthreads();
    if (t == 0) {
        double tot = 0.0;
#pragma unroll
        for (int i = 0; i < 16; ++i) tot += pd[i];
        out[ZQ_ELEMS] = (float)(1.25 * tot / 33554432.0);
    }
}

extern "C" void kernel_launch(void* const* d_in, const int* in_sizes, int n_in,
                              void* d_out, int out_size, void* d_ws, size_t ws_size,
                              hipStream_t stream) {
    const float* z  = (const float*)d_in[0];   // (16,512,64,64) fp32
    const float* cb = (const float*)d_in[1];   // (1024,512) fp32
    float* out = (float*)d_out;                // [z_q | loss | indices(float)]
    char* ws = (char*)d_ws;

    float* ynorm    = (float*)(ws + 1024);                // 4 KB
    int*   ws_idx   = (int*)(ws + 8192);                  // 256 KB
    float* dpart    = (float*)(ws + 272 * 1024);          // 1 KB (256 floats)
    float* zpart    = (float*)(ws + 288 * 1024);          // 32 KB (8192 floats)
    unsigned short* Bh = (unsigned short*)(ws + (1L << 20));
    unsigned short* Bl = (unsigned short*)(ws + (2L << 20));
    const size_t base = 3L << 20;
    unsigned short* Ah = (unsigned short*)(ws + base);

    // pick M-phasing from available workspace (deterministic in ws_size)
    int nphase = 1;
    while (nphase < 16) {
        size_t Asz = (size_t)(65536 / nphase) * 512 * 2;
        if (base + 2 * Asz <= ws_size) break;
        nphase <<= 1;
    }
    size_t Asz = (size_t)(65536 / nphase) * 512 * 2;
    unsigned short* Al = (unsigned short*)(ws + base + Asz);

    vq_prep<<<N_E, 64, 0, stream>>>(cb, Bh, Bl, ynorm);
    int PM = 65536 / nphase;
    for (int p = 0; p < nphase; ++p) {
        vq_pack<<<8192 / nphase, 256, 0, stream>>>(z, Ah, Al, zpart,
                                                   p * (16 / nphase),
                                                   p * (8192 / nphase));
        vq_dist<<<PM / 256, 512, 0, stream>>>(Ah, Al, Bh, Bl, ynorm, ws_idx,
                                              out + ZQ_ELEMS + 1, dpart, p * PM);
    }
    vq_gather<<<NVEC / 256 * 32, 256, 0, stream>>>(cb, ws_idx, out);
    vq_final<<<1, 1024, 0, stream>>>(dpart, zpart, out);
}